// Round 10
// baseline (1776.433 us; speedup 1.0000x reference)
//
#include <hip/hip_runtime.h>
#include <hip/hip_fp16.h>
#include <math.h>
#include <float.h>

#define HDIM 128
#define NGRAPH 256
#define EPSBN 1e-5f
#define PS_REP 32
#define SLABF (2 * PS_REP * 128)   // floats per BN slab (psum+psq)

typedef _Float16 f16x8 __attribute__((ext_vector_type(8)));
typedef _Float16 f16x4 __attribute__((ext_vector_type(4)));
typedef float f32x4 __attribute__((ext_vector_type(4)));

__device__ inline unsigned enc_f(float v) {
  unsigned u = __float_as_uint(v);
  return (u & 0x80000000u) ? ~u : (u | 0x80000000u);
}
__device__ inline float dec_f(unsigned e) {
  return __uint_as_float((e & 0x80000000u) ? (e ^ 0x80000000u) : ~e);
}

// ---------- degree / dinv ----------
__global__ void k_deg(const int* __restrict__ dst, int* __restrict__ deg, int E) {
  int i = blockIdx.x * blockDim.x + threadIdx.x;
  if (i < E) atomicAdd(&deg[dst[i]], 1);
}

__global__ void k_dinv(const int* __restrict__ deg, float* __restrict__ dinv, int n) {
  int i = blockIdx.x * blockDim.x + threadIdx.x;
  if (i < n) dinv[i] = rsqrtf((float)deg[i] + 1.0f);
}

// ---------- 2-level exclusive scan of PADDED deg (multiple of 4) -> prow ----------
__global__ void k_scanA(const int* __restrict__ deg, int* __restrict__ rowstart,
                        int* __restrict__ bsum, int n) {
  __shared__ int s[256];
  int t = threadIdx.x, i = blockIdx.x * 256 + t;
  int v = (i < n) ? ((deg[i] + 3) & ~3) : 0;
  s[t] = v;
  __syncthreads();
  for (int off = 1; off < 256; off <<= 1) {
    int x = (t >= off) ? s[t - off] : 0;
    __syncthreads();
    s[t] += x;
    __syncthreads();
  }
  if (i < n) rowstart[i] = s[t] - v;  // exclusive
  if (t == 255) bsum[blockIdx.x] = s[255];
}

__global__ void k_scanB(int* __restrict__ bsum, int nb) {
  __shared__ int s[512];
  int t = threadIdx.x;
  int v = (t < nb) ? bsum[t] : 0;
  s[t] = v;
  __syncthreads();
  for (int off = 1; off < 512; off <<= 1) {
    int x = (t >= off) ? s[t - off] : 0;
    __syncthreads();
    s[t] += x;
    __syncthreads();
  }
  if (t < nb) bsum[t] = s[t] - v;  // exclusive
}

__global__ void k_scanC(int* __restrict__ rowstart, const int* __restrict__ bsum,
                        const int* __restrict__ deg, int n) {
  int i = blockIdx.x * 256 + threadIdx.x;
  if (i < n) {
    int v = rowstart[i] + bsum[blockIdx.x];
    rowstart[i] = v;
    if (i == n - 1) rowstart[n] = v + ((deg[i] + 3) & ~3);
  }
}

// real edges -> padded CSR slots {src_byteoff, w}; dst-windowed pass (L2-resident writes)
__global__ void k_fill(const int* __restrict__ src, const int* __restrict__ dst,
                       const float* __restrict__ dinv, const int* __restrict__ prow,
                       int* __restrict__ cursor, int2* __restrict__ csr2, int E,
                       int lo, int hi) {
  int e = blockIdx.x * blockDim.x + threadIdx.x;
  if (e < E) {
    int d = dst[e];
    if (d >= lo && d < hi) {
      int s = src[e];
      int pos = prow[d] + atomicAdd(&cursor[d], 1);
      csr2[pos] = make_int2(s << 8, __float_as_int(dinv[s] * dinv[d]));
    }
  }
}

// pad slots deg[i]..degpad-1 with {self, 0}
__global__ void k_pad(const int* __restrict__ deg, const int* __restrict__ prow,
                      int2* __restrict__ csr2, int n) {
  int i = blockIdx.x * blockDim.x + threadIdx.x;
  if (i < n) {
    int d = deg[i], dp = (d + 3) & ~3;
    int base = prow[i];
    for (int j = d; j < dp; ++j) csr2[base + j] = make_int2(i << 8, 0);
  }
}

// ---------- weight prep: fp32 [k][col] -> fp16 [col][k], 17 matrices (16 layers + Wp) ----------
__global__ __launch_bounds__(256) void k_wprep(const float* __restrict__ W1,
                                               const float* __restrict__ W2,
                                               const float* __restrict__ Wp,
                                               _Float16* __restrict__ wt) {
  int m = blockIdx.x;
  const float* Wsrc = (m == 16) ? Wp : (((m & 1) ? W2 : W1) + (size_t)(m >> 1) * 16384);
  _Float16* Wdst = wt + (size_t)m * 16384;
  __shared__ _Float16 lds[128 * 132];
  int t = threadIdx.x;
  const float4* W4 = (const float4*)Wsrc;
  for (int it = 0; it < 16; ++it) {
    int idx = t + it * 256;
    int k = idx >> 5, c4 = idx & 31;
    float4 v = W4[idx];
    lds[(c4 * 4 + 0) * 132 + k] = (_Float16)v.x;
    lds[(c4 * 4 + 1) * 132 + k] = (_Float16)v.y;
    lds[(c4 * 4 + 2) * 132 + k] = (_Float16)v.z;
    lds[(c4 * 4 + 3) * 132 + k] = (_Float16)v.w;
  }
  __syncthreads();
  for (int it = 0; it < 16; ++it) {
    int idx = t + it * 256;
    int col = idx >> 5, k4 = idx & 31;
    f16x4 o;
    o[0] = lds[col * 132 + k4 * 4 + 0];
    o[1] = lds[col * 132 + k4 * 4 + 1];
    o[2] = lds[col * 132 + k4 * 4 + 2];
    o[3] = lds[col * 132 + k4 * 4 + 3];
    *(f16x4*)(Wdst + col * 128 + k4 * 4) = o;
  }
}

// ---------- MFMA projection: out[N,128] = f16(in) @ Wp + bias (fp32 out) ----------
__global__ __launch_bounds__(256) void k_gemmp(const float* __restrict__ in,
                                               const _Float16* __restrict__ wt,
                                               const float* __restrict__ bias,
                                               float* __restrict__ out, int n) {
  __shared__ _Float16 As[64 * 128];
  __shared__ _Float16 Bs[128 * 128];
  char* Ap = (char*)As;
  char* Bp = (char*)Bs;
  int tid = threadIdx.x;
  int lane = tid & 63;
  int rt = tid >> 6;
  int row0 = blockIdx.x * 64;

  for (int it = 0; it < 8; ++it) {
    int idx = tid + it * 256;
    int r = idx >> 5, c4 = idx & 31;
    int row = row0 + r;
    if (row >= n) row = n - 1;
    float4 v = *(const float4*)(in + (size_t)row * 128 + c4 * 4);
    f16x4 hv;
    hv[0] = (_Float16)v.x; hv[1] = (_Float16)v.y;
    hv[2] = (_Float16)v.z; hv[3] = (_Float16)v.w;
    *(f16x4*)(Ap + ((r * 256 + c4 * 8) ^ ((r & 7) << 4))) = hv;
  }
  for (int it = 0; it < 8; ++it) {
    int idx = tid + it * 256;
    int col = idx >> 4, k8 = idx & 15;
    f16x8 v = *(const f16x8*)(wt + col * 128 + k8 * 8);
    *(f16x8*)(Bp + ((col * 256 + k8 * 16) ^ ((col & 7) << 4))) = v;
  }
  __syncthreads();

  f32x4 acc[8];
#pragma unroll
  for (int ct = 0; ct < 8; ++ct) acc[ct] = (f32x4){0.f, 0.f, 0.f, 0.f};
  int arow = rt * 16 + (lane & 15);
  int kc = (lane >> 4) * 16;
#pragma unroll
  for (int ks = 0; ks < 4; ++ks) {
    int kb = ks * 64;
    f16x8 a = *(f16x8*)(Ap + ((arow * 256 + kb + kc) ^ ((arow & 7) << 4)));
#pragma unroll
    for (int ct = 0; ct < 8; ++ct) {
      int bcol = ct * 16 + (lane & 15);
      f16x8 b = *(f16x8*)(Bp + ((bcol * 256 + kb + kc) ^ ((bcol & 7) << 4)));
      acc[ct] = __builtin_amdgcn_mfma_f32_16x16x32_f16(a, b, acc[ct], 0, 0, 0);
    }
  }

  int orow0 = row0 + rt * 16 + (lane >> 4) * 4;
#pragma unroll
  for (int ct = 0; ct < 8; ++ct) {
    int col = ct * 16 + (lane & 15);
    float bb = bias[col];
#pragma unroll
    for (int r = 0; r < 4; ++r) {
      int row = orow0 + r;
      if (row < n) out[(size_t)row * 128 + col] = acc[ct][r] + bb;
    }
  }
}

// ---------- MFMA f16 GEMM with BN prologue ----------
// XFORM=0: in fp32, plain.
// XFORM=1: in f16 (t2); in := relu(in*sc+sh); sc/sh from psumL slab.
// XFORM=2: in f16 (t2); in := hres + in*sc+sh (BN2+residual); writes new hres.
template <int XFORM>
__global__ __launch_bounds__(256) void k_gemmh(const void* __restrict__ inp,
                                               const _Float16* __restrict__ wt,
                                               const float* __restrict__ psumL,
                                               const float* __restrict__ gg,
                                               const float* __restrict__ be,
                                               float* __restrict__ hres,
                                               _Float16* __restrict__ outh, int n) {
  __shared__ _Float16 As[64 * 128];
  __shared__ _Float16 Bs[128 * 128];
  __shared__ float sc_s[128], sh_s[128];
  char* Ap = (char*)As;
  char* Bp = (char*)Bs;
  int tid = threadIdx.x;
  int lane = tid & 63;
  int rt = tid >> 6;
  int row0 = blockIdx.x * 64;

  if (XFORM) {
    if (tid < 128) {
      const float* psqL = psumL + PS_REP * 128;
      float s = 0.f, q = 0.f;
#pragma unroll 8
      for (int r = 0; r < PS_REP; ++r) {
        s += psumL[r * 128 + tid];
        q += psqL[r * 128 + tid];
      }
      float mu = s / (float)n;
      float var = q / (float)n - mu * mu;
      float rs = rsqrtf(var + EPSBN);
      float sc = gg[tid] * rs;
      sc_s[tid] = sc;
      sh_s[tid] = be[tid] - mu * sc;
    }
    __syncthreads();
  }

  if (XFORM == 0) {
    const float* in = (const float*)inp;
    for (int it = 0; it < 8; ++it) {
      int idx = tid + it * 256;
      int r = idx >> 5, c4 = idx & 31;
      int row = row0 + r;
      if (row >= n) row = n - 1;
      float4 v = *(const float4*)(in + (size_t)row * 128 + c4 * 4);
      f16x4 hv16;
      hv16[0] = (_Float16)v.x; hv16[1] = (_Float16)v.y;
      hv16[2] = (_Float16)v.z; hv16[3] = (_Float16)v.w;
      *(f16x4*)(Ap + ((r * 256 + c4 * 8) ^ ((r & 7) << 4))) = hv16;
    }
  } else {
    const _Float16* in = (const _Float16*)inp;
    for (int it = 0; it < 4; ++it) {
      int idx = tid + it * 256;          // 1024 chunks of 8 cols
      int r = idx >> 4, c8 = idx & 15;
      int rrow = row0 + r;
      int row = (rrow >= n) ? (n - 1) : rrow;
      f16x8 tv = *(const f16x8*)(in + (size_t)row * 128 + c8 * 8);
      float4 s0 = *(const float4*)(sc_s + c8 * 8);
      float4 s1 = *(const float4*)(sc_s + c8 * 8 + 4);
      float4 h0 = *(const float4*)(sh_s + c8 * 8);
      float4 h1 = *(const float4*)(sh_s + c8 * 8 + 4);
      float v[8];
#pragma unroll
      for (int j = 0; j < 8; ++j) v[j] = (float)tv[j];
      v[0] = v[0] * s0.x + h0.x; v[1] = v[1] * s0.y + h0.y;
      v[2] = v[2] * s0.z + h0.z; v[3] = v[3] * s0.w + h0.w;
      v[4] = v[4] * s1.x + h1.x; v[5] = v[5] * s1.y + h1.y;
      v[6] = v[6] * s1.z + h1.z; v[7] = v[7] * s1.w + h1.w;
      if (XFORM == 1) {
#pragma unroll
        for (int j = 0; j < 8; ++j) v[j] = fmaxf(v[j], 0.f);
      }
      if (XFORM == 2) {
        float4 hv0 = *(const float4*)(hres + (size_t)row * 128 + c8 * 8);
        float4 hv1 = *(const float4*)(hres + (size_t)row * 128 + c8 * 8 + 4);
        v[0] += hv0.x; v[1] += hv0.y; v[2] += hv0.z; v[3] += hv0.w;
        v[4] += hv1.x; v[5] += hv1.y; v[6] += hv1.z; v[7] += hv1.w;
        if (rrow < n) {
          *(float4*)(hres + (size_t)row * 128 + c8 * 8) = make_float4(v[0], v[1], v[2], v[3]);
          *(float4*)(hres + (size_t)row * 128 + c8 * 8 + 4) = make_float4(v[4], v[5], v[6], v[7]);
        }
      }
      f16x8 o;
#pragma unroll
      for (int j = 0; j < 8; ++j) o[j] = (_Float16)v[j];
      *(f16x8*)(Ap + ((r * 256 + c8 * 16) ^ ((r & 7) << 4))) = o;
    }
  }
  for (int it = 0; it < 8; ++it) {
    int idx = tid + it * 256;
    int col = idx >> 4, k8 = idx & 15;
    f16x8 v = *(const f16x8*)(wt + col * 128 + k8 * 8);
    *(f16x8*)(Bp + ((col * 256 + k8 * 16) ^ ((col & 7) << 4))) = v;
  }
  __syncthreads();

  f32x4 acc[8];
#pragma unroll
  for (int ct = 0; ct < 8; ++ct) acc[ct] = (f32x4){0.f, 0.f, 0.f, 0.f};

  int arow = rt * 16 + (lane & 15);
  int kc = (lane >> 4) * 16;
#pragma unroll
  for (int ks = 0; ks < 4; ++ks) {
    int kb = ks * 64;
    f16x8 a = *(f16x8*)(Ap + ((arow * 256 + kb + kc) ^ ((arow & 7) << 4)));
#pragma unroll
    for (int ct = 0; ct < 8; ++ct) {
      int bcol = ct * 16 + (lane & 15);
      f16x8 b = *(f16x8*)(Bp + ((bcol * 256 + kb + kc) ^ ((bcol & 7) << 4)));
      acc[ct] = __builtin_amdgcn_mfma_f32_16x16x32_f16(a, b, acc[ct], 0, 0, 0);
    }
  }

  int orow0 = row0 + rt * 16 + (lane >> 4) * 4;
#pragma unroll
  for (int ct = 0; ct < 8; ++ct) {
    int col = ct * 16 + (lane & 15);
#pragma unroll
    for (int r = 0; r < 4; ++r) {
      int row = orow0 + r;
      if (row < n) outh[(size_t)row * 128 + col] = (_Float16)acc[ct][r];
    }
  }
}

// ---------- edge aggregation: wave-per-node, 8-edge windows, packed-f16 accumulate ----------
// 4 groups of 16 lanes; per window group g reads int4 = csr{e+2g,e+2g+1}, gathers both
// rows (f16x8/lane), accumulates with v_pk_fma_f16 (4 instrs/edge vs 32 f32 cvt+fma).
__global__ __launch_bounds__(256) void k_agg(const _Float16* __restrict__ hw,
                                             const int* __restrict__ prow,
                                             const int2* __restrict__ csr2,
                                             const float* __restrict__ dinv,
                                             const float* __restrict__ bias,
                                             _Float16* __restrict__ out,
                                             float* __restrict__ psumL, int n) {
  int wave = threadIdx.x >> 6;
  int lane = threadIdx.x & 63;
  int grp = lane >> 4;   // 0..3
  int l16 = lane & 15;   // 0..15
  int node = blockIdx.x * 4 + wave;
  float a[8];
#pragma unroll
  for (int j = 0; j < 8; ++j) a[j] = 0.f;

  if (node < n) {
    f16x8 aa = {0, 0, 0, 0, 0, 0, 0, 0};
    f16x8 ab = {0, 0, 0, 0, 0, 0, 0, 0};
    int e0 = prow[node], e1 = prow[node + 1];
    int len = e1 - e0;
    int e = e0;
    int end8 = e0 + (len & ~7);
    const char* base = (const char*)hw + l16 * 16;
    for (; e < end8; e += 8) {
      int4 pq = *(const int4*)(csr2 + e + 2 * grp);   // edges e+2g, e+2g+1
      _Float16 w0 = (_Float16)__int_as_float(pq.y);
      _Float16 w1 = (_Float16)__int_as_float(pq.w);
      f16x8 v0 = *(const f16x8*)(base + (unsigned)pq.x);
      f16x8 v1 = *(const f16x8*)(base + (unsigned)pq.z);
      aa += v0 * w0;   // 4x v_pk_fma_f16
      ab += v1 * w1;
    }
    if (len & 4) {  // wave-uniform tail window of 4 edges
      int2 p = csr2[e + grp];
      _Float16 w = (_Float16)__int_as_float(p.y);
      f16x8 v = *(const f16x8*)(base + (unsigned)p.x);
      aa += v * w;
    }
    aa += ab;
#pragma unroll
    for (int j = 0; j < 8; ++j) a[j] = (float)aa[j];
    // reduce across the 4 groups (lanes differ in bits 4,5)
#pragma unroll
    for (int j = 0; j < 8; ++j) {
      a[j] += __shfl_xor(a[j], 16);
      a[j] += __shfl_xor(a[j], 32);
    }
    float dn = dinv[node];
    float sn = dn * dn;
    f16x8 v = *(const f16x8*)(hw + (size_t)node * 128 + l16 * 8);
    float4 bb0 = *(const float4*)(bias + l16 * 8);
    float4 bb1 = *(const float4*)(bias + l16 * 8 + 4);
    a[0] += sn * (float)v[0] + bb0.x;
    a[1] += sn * (float)v[1] + bb0.y;
    a[2] += sn * (float)v[2] + bb0.z;
    a[3] += sn * (float)v[3] + bb0.w;
    a[4] += sn * (float)v[4] + bb1.x;
    a[5] += sn * (float)v[5] + bb1.y;
    a[6] += sn * (float)v[6] + bb1.z;
    a[7] += sn * (float)v[7] + bb1.w;
    if (grp == 0) {
      f16x8 ov;
#pragma unroll
      for (int j = 0; j < 8; ++j) ov[j] = (_Float16)a[j];
      *(f16x8*)(out + (size_t)node * 128 + l16 * 8) = ov;
    }
  }
  // fused BN stats (fp32 pre-rounding): LDS reduce, replicated atomics
  __shared__ float ss[4][128];
  __shared__ float sq[4][128];
  if (grp == 0) {
    bool live = (node < n);
    float v0 = live ? a[0] : 0.f, v1 = live ? a[1] : 0.f;
    float v2 = live ? a[2] : 0.f, v3 = live ? a[3] : 0.f;
    float v4 = live ? a[4] : 0.f, v5 = live ? a[5] : 0.f;
    float v6 = live ? a[6] : 0.f, v7 = live ? a[7] : 0.f;
    *(float4*)&ss[wave][l16 * 8] = make_float4(v0, v1, v2, v3);
    *(float4*)&ss[wave][l16 * 8 + 4] = make_float4(v4, v5, v6, v7);
    *(float4*)&sq[wave][l16 * 8] = make_float4(v0 * v0, v1 * v1, v2 * v2, v3 * v3);
    *(float4*)&sq[wave][l16 * 8 + 4] = make_float4(v4 * v4, v5 * v5, v6 * v6, v7 * v7);
  }
  __syncthreads();
  int t = threadIdx.x;
  if (t < 128) {
    float s = (ss[0][t] + ss[1][t]) + (ss[2][t] + ss[3][t]);
    float q = (sq[0][t] + sq[1][t]) + (sq[2][t] + sq[3][t]);
    int rep = blockIdx.x & (PS_REP - 1);
    atomicAdd(&psumL[rep * 128 + t], s);
    atomicAdd(&psumL[PS_REP * 128 + rep * 128 + t], q);
  }
}

// ---------- pooling (absorbs final BN2+residual): batch sorted -> segment reduction ----------
#define PCHUNK 128
__global__ __launch_bounds__(128) void k_pool(const float* __restrict__ h,
                                              const _Float16* __restrict__ t2h,
                                              const float* __restrict__ psumL,
                                              const float* __restrict__ gg,
                                              const float* __restrict__ be,
                                              const int* __restrict__ batch,
                                              float* __restrict__ sums,
                                              unsigned* __restrict__ maxenc,
                                              int* __restrict__ cnt, int n) {
  int c = threadIdx.x;
  __shared__ float sc_s[128], sh_s[128];
  {
    const float* psqL = psumL + PS_REP * 128;
    float s = 0.f, q = 0.f;
#pragma unroll 8
    for (int r = 0; r < PS_REP; ++r) {
      s += psumL[r * 128 + c];
      q += psqL[r * 128 + c];
    }
    float mu = s / (float)n;
    float var = q / (float)n - mu * mu;
    float rs = rsqrtf(var + EPSBN);
    float sc = gg[c] * rs;
    sc_s[c] = sc;
    sh_s[c] = be[c] - mu * sc;
  }
  __syncthreads();
  float scc = sc_s[c], shc = sh_s[c];

  int start = blockIdx.x * PCHUNK;
  if (start >= n) return;
  int end = start + PCHUNK;
  if (end > n) end = n;
  int cur = batch[start];
  float s = 0.f, mx = -FLT_MAX;
  int runlen = 0;
  for (int i = start; i < end; ++i) {
    int b = batch[i];
    if (b != cur) {
      atomicAdd(&sums[cur * 128 + c], s);
      atomicMax(&maxenc[cur * 128 + c], enc_f(mx));
      if (c == 0) atomicAdd(&cnt[cur], runlen);
      s = 0.f; mx = -FLT_MAX; runlen = 0; cur = b;
    }
    float v = h[(size_t)i * 128 + c] + scc * (float)t2h[(size_t)i * 128 + c] + shc;
    s += v;
    mx = fmaxf(mx, v);
    runlen++;
  }
  atomicAdd(&sums[cur * 128 + c], s);
  atomicMax(&maxenc[cur * 128 + c], enc_f(mx));
  if (c == 0) atomicAdd(&cnt[cur], runlen);
}

// ---------- readout MLP ----------
__global__ __launch_bounds__(256) void k_readout(const float* __restrict__ sums,
                                                 const unsigned* __restrict__ maxenc,
                                                 const int* __restrict__ cnt,
                                                 const float* __restrict__ Wa,
                                                 const float* __restrict__ ba,
                                                 const float* __restrict__ Wb,
                                                 const float* __restrict__ bb,
                                                 const float* __restrict__ Wc,
                                                 const float* __restrict__ bc,
                                                 float* __restrict__ out) {
  int g = blockIdx.x;
  int t = threadIdx.x;
  __shared__ float z[384];
  __shared__ float za[256];
  __shared__ float zb[128];
  float c = (float)(cnt[g] > 1 ? cnt[g] : 1);
  if (t < 128) {
    float s = sums[g * 128 + t];
    z[t] = s / c;
    z[128 + t] = dec_f(maxenc[g * 128 + t]);
    z[256 + t] = s;
  }
  __syncthreads();
  float accA = ba[t];
  for (int k = 0; k < 384; k++) accA += z[k] * Wa[k * 256 + t];
  za[t] = fmaxf(accA, 0.f);
  __syncthreads();
  if (t < 128) {
    float accB = bb[t];
    for (int k = 0; k < 256; k++) accB += za[k] * Wb[k * 128 + t];
    zb[t] = fmaxf(accB, 0.f);
  }
  __syncthreads();
  if (t < 64) {
    float p = zb[t] * Wc[t] + zb[t + 64] * Wc[t + 64];
    for (int off = 32; off > 0; off >>= 1) p += __shfl_down(p, off);
    if (t == 0) out[g] = p + bc[0];
  }
}

extern "C" void kernel_launch(void* const* d_in, const int* in_sizes, int n_in,
                              void* d_out, int out_size, void* d_ws, size_t ws_size,
                              hipStream_t stream) {
  const float* x   = (const float*)d_in[0];
  const int* edge  = (const int*)d_in[1];
  const int* batch = (const int*)d_in[2];
  const float* Wp  = (const float*)d_in[3];
  const float* bp  = (const float*)d_in[4];
  const float* W1  = (const float*)d_in[5];
  const float* b1  = (const float*)d_in[6];
  const float* g1  = (const float*)d_in[7];
  const float* be1 = (const float*)d_in[8];
  const float* W2  = (const float*)d_in[9];
  const float* b2  = (const float*)d_in[10];
  const float* g2  = (const float*)d_in[11];
  const float* be2 = (const float*)d_in[12];
  const float* Wa  = (const float*)d_in[13];
  const float* ba  = (const float*)d_in[14];
  const float* Wb  = (const float*)d_in[15];
  const float* bbp = (const float*)d_in[16];
  const float* Wc  = (const float*)d_in[17];
  const float* bc  = (const float*)d_in[18];
  float* out = (float*)d_out;

  const int N = in_sizes[0] / 128;
  const int E = in_sizes[1] / 2;
  const int* esrc = edge;
  const int* edst = edge + E;

  char* p = (char*)d_ws;
  auto carve = [&](size_t bytes) {
    char* r = p;
    p += (bytes + 255) & ~(size_t)255;
    return (void*)r;
  };
  float* h    = (float*)carve((size_t)N * 128 * 4);
  _Float16* t1h = (_Float16*)carve((size_t)N * 128 * 2);
  _Float16* t2h = (_Float16*)carve((size_t)N * 128 * 2);
  int2* csr2  = (int2*)carve(((size_t)E + 4 * (size_t)N) * 8);  // padded CSR
  int* deg     = (int*)carve((size_t)N * 4);
  float* dinv  = (float*)carve((size_t)N * 4);
  int* prow    = (int*)carve((size_t)(N + 1) * 4);
  int* cursor  = (int*)carve((size_t)N * 4);
  int* bsum    = (int*)carve(512 * 4);
  float* slab  = (float*)carve((size_t)16 * SLABF * 4);  // 16 BN slabs
  float* pools = (float*)carve((size_t)NGRAPH * 128 * 4);
  unsigned* poolm = (unsigned*)carve((size_t)NGRAPH * 128 * 4);
  int* poolc      = (int*)carve(NGRAPH * 4);
  _Float16* wt16  = (_Float16*)carve((size_t)17 * 128 * 128 * 2);

  const int NB = (N + 255) / 256;

  hipMemsetAsync(deg, 0, (size_t)N * 4, stream);
  hipMemsetAsync(cursor, 0, (size_t)N * 4, stream);
  hipMemsetAsync(slab, 0, (size_t)16 * SLABF * 4, stream);
  hipMemsetAsync(pools, 0, (size_t)NGRAPH * 128 * 4, stream);
  hipMemsetAsync(poolm, 0, (size_t)NGRAPH * 128 * 4, stream);
  hipMemsetAsync(poolc, 0, (size_t)NGRAPH * 4, stream);

  k_deg<<<(E + 255) / 256, 256, 0, stream>>>(edst, deg, E);
  k_dinv<<<NB, 256, 0, stream>>>(deg, dinv, N);
  k_scanA<<<NB, 256, 0, stream>>>(deg, prow, bsum, N);
  k_scanB<<<1, 512, 0, stream>>>(bsum, NB);
  k_scanC<<<NB, 256, 0, stream>>>(prow, bsum, deg, N);
  // dst-windowed CSR fill: 4 passes, each writing an L2-resident csr2 window
  for (int pp = 0; pp < 4; ++pp) {
    int lo = (int)((long long)N * pp / 4);
    int hi = (int)((long long)N * (pp + 1) / 4);
    k_fill<<<(E + 255) / 256, 256, 0, stream>>>(esrc, edst, dinv, prow, cursor, csr2, E, lo, hi);
  }
  k_pad<<<NB, 256, 0, stream>>>(deg, prow, csr2, N);
  k_wprep<<<17, 256, 0, stream>>>(W1, W2, Wp, wt16);

  const int GB = (N + 63) / 64;
  const int AB = (N + 3) / 4;
  const int PB = (N + PCHUNK - 1) / PCHUNK;

  k_gemmp<<<GB, 256, 0, stream>>>(x, wt16 + (size_t)16 * 16384, bp, h, N);
  k_gemmh<0><<<GB, 256, 0, stream>>>(h, wt16, nullptr, nullptr, nullptr, nullptr, t1h, N);

  for (int l = 0; l < 8; l++) {
    const _Float16* w2t = wt16 + (size_t)(l * 2 + 1) * 16384;
    float* slab1 = slab + (size_t)(2 * l) * SLABF;
    float* slab2 = slab + (size_t)(2 * l + 1) * SLABF;
    k_agg<<<AB, 256, 0, stream>>>(t1h, prow, csr2, dinv, b1 + l * 128, t2h, slab1, N);
    k_gemmh<1><<<GB, 256, 0, stream>>>(t2h, w2t, slab1, g1 + l * 128, be1 + l * 128, nullptr, t1h, N);
    k_agg<<<AB, 256, 0, stream>>>(t1h, prow, csr2, dinv, b2 + l * 128, t2h, slab2, N);
    if (l < 7) {
      const _Float16* w1n = wt16 + (size_t)((l + 1) * 2) * 16384;
      k_gemmh<2><<<GB, 256, 0, stream>>>(t2h, w1n, slab2, g2 + l * 128, be2 + l * 128, h, t1h, N);
    }
  }

  k_pool<<<PB, 128, 0, stream>>>(h, t2h, slab + (size_t)15 * SLABF, g2 + 7 * 128, be2 + 7 * 128,
                                 batch, pools, poolm, poolc, N);
  k_readout<<<NGRAPH, 256, 0, stream>>>(pools, poolm, poolc, Wa, ba, Wb, bbp, Wc, bc, out);
}

// Round 11
// 1717.555 us; speedup vs baseline: 1.0343x; 1.0343x over previous
//
#include <hip/hip_runtime.h>
#include <hip/hip_fp16.h>
#include <math.h>
#include <float.h>

#define HDIM 128
#define NGRAPH 256
#define EPSBN 1e-5f
#define PS_REP 32
#define SLABF (2 * PS_REP * 128)   // floats per BN slab (psum+psq)

typedef _Float16 f16x8 __attribute__((ext_vector_type(8)));
typedef _Float16 f16x4 __attribute__((ext_vector_type(4)));
typedef float f32x4 __attribute__((ext_vector_type(4)));

__device__ inline unsigned enc_f(float v) {
  unsigned u = __float_as_uint(v);
  return (u & 0x80000000u) ? ~u : (u | 0x80000000u);
}
__device__ inline float dec_f(unsigned e) {
  return __uint_as_float((e & 0x80000000u) ? (e ^ 0x80000000u) : ~e);
}

// ---------- degree / dinv ----------
__global__ void k_deg(const int* __restrict__ dst, int* __restrict__ deg, int E) {
  int i = blockIdx.x * blockDim.x + threadIdx.x;
  if (i < E) atomicAdd(&deg[dst[i]], 1);
}

__global__ void k_dinv(const int* __restrict__ deg, float* __restrict__ dinv, int n) {
  int i = blockIdx.x * blockDim.x + threadIdx.x;
  if (i < n) dinv[i] = rsqrtf((float)deg[i] + 1.0f);
}

// ---------- 2-level exclusive scan of PADDED deg (multiple of 4) -> prow ----------
__global__ void k_scanA(const int* __restrict__ deg, int* __restrict__ rowstart,
                        int* __restrict__ bsum, int n) {
  __shared__ int s[256];
  int t = threadIdx.x, i = blockIdx.x * 256 + t;
  int v = (i < n) ? ((deg[i] + 3) & ~3) : 0;
  s[t] = v;
  __syncthreads();
  for (int off = 1; off < 256; off <<= 1) {
    int x = (t >= off) ? s[t - off] : 0;
    __syncthreads();
    s[t] += x;
    __syncthreads();
  }
  if (i < n) rowstart[i] = s[t] - v;  // exclusive
  if (t == 255) bsum[blockIdx.x] = s[255];
}

__global__ void k_scanB(int* __restrict__ bsum, int nb) {
  __shared__ int s[512];
  int t = threadIdx.x;
  int v = (t < nb) ? bsum[t] : 0;
  s[t] = v;
  __syncthreads();
  for (int off = 1; off < 512; off <<= 1) {
    int x = (t >= off) ? s[t - off] : 0;
    __syncthreads();
    s[t] += x;
    __syncthreads();
  }
  if (t < nb) bsum[t] = s[t] - v;  // exclusive
}

__global__ void k_scanC(int* __restrict__ rowstart, const int* __restrict__ bsum,
                        const int* __restrict__ deg, int n) {
  int i = blockIdx.x * 256 + threadIdx.x;
  if (i < n) {
    int v = rowstart[i] + bsum[blockIdx.x];
    rowstart[i] = v;
    if (i == n - 1) rowstart[n] = v + ((deg[i] + 3) & ~3);
  }
}

// real edges -> padded CSR slots {src_byteoff, w} (single pass)
__global__ void k_fill(const int* __restrict__ src, const int* __restrict__ dst,
                       const float* __restrict__ dinv, const int* __restrict__ prow,
                       int* __restrict__ cursor, int2* __restrict__ csr2, int E) {
  int e = blockIdx.x * blockDim.x + threadIdx.x;
  if (e < E) {
    int d = dst[e], s = src[e];
    int pos = prow[d] + atomicAdd(&cursor[d], 1);
    csr2[pos] = make_int2(s << 8, __float_as_int(dinv[s] * dinv[d]));
  }
}

// pad slots deg[i]..degpad-1 with {self, 0}
__global__ void k_pad(const int* __restrict__ deg, const int* __restrict__ prow,
                      int2* __restrict__ csr2, int n) {
  int i = blockIdx.x * blockDim.x + threadIdx.x;
  if (i < n) {
    int d = deg[i], dp = (d + 3) & ~3;
    int base = prow[i];
    for (int j = d; j < dp; ++j) csr2[base + j] = make_int2(i << 8, 0);
  }
}

// ---------- weight prep: fp32 [k][col] -> fp16 [col][k], 17 matrices (16 layers + Wp) ----------
__global__ __launch_bounds__(256) void k_wprep(const float* __restrict__ W1,
                                               const float* __restrict__ W2,
                                               const float* __restrict__ Wp,
                                               _Float16* __restrict__ wt) {
  int m = blockIdx.x;
  const float* Wsrc = (m == 16) ? Wp : (((m & 1) ? W2 : W1) + (size_t)(m >> 1) * 16384);
  _Float16* Wdst = wt + (size_t)m * 16384;
  __shared__ _Float16 lds[128 * 132];
  int t = threadIdx.x;
  const float4* W4 = (const float4*)Wsrc;
  for (int it = 0; it < 16; ++it) {
    int idx = t + it * 256;
    int k = idx >> 5, c4 = idx & 31;
    float4 v = W4[idx];
    lds[(c4 * 4 + 0) * 132 + k] = (_Float16)v.x;
    lds[(c4 * 4 + 1) * 132 + k] = (_Float16)v.y;
    lds[(c4 * 4 + 2) * 132 + k] = (_Float16)v.z;
    lds[(c4 * 4 + 3) * 132 + k] = (_Float16)v.w;
  }
  __syncthreads();
  for (int it = 0; it < 16; ++it) {
    int idx = t + it * 256;
    int col = idx >> 5, k4 = idx & 31;
    f16x4 o;
    o[0] = lds[col * 132 + k4 * 4 + 0];
    o[1] = lds[col * 132 + k4 * 4 + 1];
    o[2] = lds[col * 132 + k4 * 4 + 2];
    o[3] = lds[col * 132 + k4 * 4 + 3];
    *(f16x4*)(Wdst + col * 128 + k4 * 4) = o;
  }
}

// ---------- MFMA projection: out[N,128] = f16(in) @ Wp + bias (fp32 out) ----------
__global__ __launch_bounds__(256) void k_gemmp(const float* __restrict__ in,
                                               const _Float16* __restrict__ wt,
                                               const float* __restrict__ bias,
                                               float* __restrict__ out, int n) {
  __shared__ _Float16 As[64 * 128];
  __shared__ _Float16 Bs[128 * 128];
  char* Ap = (char*)As;
  char* Bp = (char*)Bs;
  int tid = threadIdx.x;
  int lane = tid & 63;
  int rt = tid >> 6;
  int row0 = blockIdx.x * 64;

  for (int it = 0; it < 8; ++it) {
    int idx = tid + it * 256;
    int r = idx >> 5, c4 = idx & 31;
    int row = row0 + r;
    if (row >= n) row = n - 1;
    float4 v = *(const float4*)(in + (size_t)row * 128 + c4 * 4);
    f16x4 hv;
    hv[0] = (_Float16)v.x; hv[1] = (_Float16)v.y;
    hv[2] = (_Float16)v.z; hv[3] = (_Float16)v.w;
    *(f16x4*)(Ap + ((r * 256 + c4 * 8) ^ ((r & 7) << 4))) = hv;
  }
  for (int it = 0; it < 8; ++it) {
    int idx = tid + it * 256;
    int col = idx >> 4, k8 = idx & 15;
    f16x8 v = *(const f16x8*)(wt + col * 128 + k8 * 8);
    *(f16x8*)(Bp + ((col * 256 + k8 * 16) ^ ((col & 7) << 4))) = v;
  }
  __syncthreads();

  f32x4 acc[8];
#pragma unroll
  for (int ct = 0; ct < 8; ++ct) acc[ct] = (f32x4){0.f, 0.f, 0.f, 0.f};
  int arow = rt * 16 + (lane & 15);
  int kc = (lane >> 4) * 16;
#pragma unroll
  for (int ks = 0; ks < 4; ++ks) {
    int kb = ks * 64;
    f16x8 a = *(f16x8*)(Ap + ((arow * 256 + kb + kc) ^ ((arow & 7) << 4)));
#pragma unroll
    for (int ct = 0; ct < 8; ++ct) {
      int bcol = ct * 16 + (lane & 15);
      f16x8 b = *(f16x8*)(Bp + ((bcol * 256 + kb + kc) ^ ((bcol & 7) << 4)));
      acc[ct] = __builtin_amdgcn_mfma_f32_16x16x32_f16(a, b, acc[ct], 0, 0, 0);
    }
  }

  int orow0 = row0 + rt * 16 + (lane >> 4) * 4;
#pragma unroll
  for (int ct = 0; ct < 8; ++ct) {
    int col = ct * 16 + (lane & 15);
    float bb = bias[col];
#pragma unroll
    for (int r = 0; r < 4; ++r) {
      int row = orow0 + r;
      if (row < n) out[(size_t)row * 128 + col] = acc[ct][r] + bb;
    }
  }
}

// ---------- MFMA f16 GEMM with BN prologue ----------
// XFORM=0: in fp32, plain.
// XFORM=1: in f16 (t2); in := relu(in*sc+sh); sc/sh from psumL slab.
// XFORM=2: in f16 (t2); in := hres + in*sc+sh (BN2+residual); writes new hres.
template <int XFORM>
__global__ __launch_bounds__(256) void k_gemmh(const void* __restrict__ inp,
                                               const _Float16* __restrict__ wt,
                                               const float* __restrict__ psumL,
                                               const float* __restrict__ gg,
                                               const float* __restrict__ be,
                                               float* __restrict__ hres,
                                               _Float16* __restrict__ outh, int n) {
  __shared__ _Float16 As[64 * 128];
  __shared__ _Float16 Bs[128 * 128];
  __shared__ float sc_s[128], sh_s[128];
  char* Ap = (char*)As;
  char* Bp = (char*)Bs;
  int tid = threadIdx.x;
  int lane = tid & 63;
  int rt = tid >> 6;
  int row0 = blockIdx.x * 64;

  if (XFORM) {
    if (tid < 128) {
      const float* psqL = psumL + PS_REP * 128;
      float s = 0.f, q = 0.f;
#pragma unroll 8
      for (int r = 0; r < PS_REP; ++r) {
        s += psumL[r * 128 + tid];
        q += psqL[r * 128 + tid];
      }
      float mu = s / (float)n;
      float var = q / (float)n - mu * mu;
      float rs = rsqrtf(var + EPSBN);
      float sc = gg[tid] * rs;
      sc_s[tid] = sc;
      sh_s[tid] = be[tid] - mu * sc;
    }
    __syncthreads();
  }

  if (XFORM == 0) {
    const float* in = (const float*)inp;
    for (int it = 0; it < 8; ++it) {
      int idx = tid + it * 256;
      int r = idx >> 5, c4 = idx & 31;
      int row = row0 + r;
      if (row >= n) row = n - 1;
      float4 v = *(const float4*)(in + (size_t)row * 128 + c4 * 4);
      f16x4 hv16;
      hv16[0] = (_Float16)v.x; hv16[1] = (_Float16)v.y;
      hv16[2] = (_Float16)v.z; hv16[3] = (_Float16)v.w;
      *(f16x4*)(Ap + ((r * 256 + c4 * 8) ^ ((r & 7) << 4))) = hv16;
    }
  } else {
    const _Float16* in = (const _Float16*)inp;
    for (int it = 0; it < 4; ++it) {
      int idx = tid + it * 256;          // 1024 chunks of 8 cols
      int r = idx >> 4, c8 = idx & 15;
      int rrow = row0 + r;
      int row = (rrow >= n) ? (n - 1) : rrow;
      f16x8 tv = *(const f16x8*)(in + (size_t)row * 128 + c8 * 8);
      float4 s0 = *(const float4*)(sc_s + c8 * 8);
      float4 s1 = *(const float4*)(sc_s + c8 * 8 + 4);
      float4 h0 = *(const float4*)(sh_s + c8 * 8);
      float4 h1 = *(const float4*)(sh_s + c8 * 8 + 4);
      float v[8];
#pragma unroll
      for (int j = 0; j < 8; ++j) v[j] = (float)tv[j];
      v[0] = v[0] * s0.x + h0.x; v[1] = v[1] * s0.y + h0.y;
      v[2] = v[2] * s0.z + h0.z; v[3] = v[3] * s0.w + h0.w;
      v[4] = v[4] * s1.x + h1.x; v[5] = v[5] * s1.y + h1.y;
      v[6] = v[6] * s1.z + h1.z; v[7] = v[7] * s1.w + h1.w;
      if (XFORM == 1) {
#pragma unroll
        for (int j = 0; j < 8; ++j) v[j] = fmaxf(v[j], 0.f);
      }
      if (XFORM == 2) {
        float4 hv0 = *(const float4*)(hres + (size_t)row * 128 + c8 * 8);
        float4 hv1 = *(const float4*)(hres + (size_t)row * 128 + c8 * 8 + 4);
        v[0] += hv0.x; v[1] += hv0.y; v[2] += hv0.z; v[3] += hv0.w;
        v[4] += hv1.x; v[5] += hv1.y; v[6] += hv1.z; v[7] += hv1.w;
        if (rrow < n) {
          *(float4*)(hres + (size_t)row * 128 + c8 * 8) = make_float4(v[0], v[1], v[2], v[3]);
          *(float4*)(hres + (size_t)row * 128 + c8 * 8 + 4) = make_float4(v[4], v[5], v[6], v[7]);
        }
      }
      f16x8 o;
#pragma unroll
      for (int j = 0; j < 8; ++j) o[j] = (_Float16)v[j];
      *(f16x8*)(Ap + ((r * 256 + c8 * 16) ^ ((r & 7) << 4))) = o;
    }
  }
  for (int it = 0; it < 8; ++it) {
    int idx = tid + it * 256;
    int col = idx >> 4, k8 = idx & 15;
    f16x8 v = *(const f16x8*)(wt + col * 128 + k8 * 8);
    *(f16x8*)(Bp + ((col * 256 + k8 * 16) ^ ((col & 7) << 4))) = v;
  }
  __syncthreads();

  f32x4 acc[8];
#pragma unroll
  for (int ct = 0; ct < 8; ++ct) acc[ct] = (f32x4){0.f, 0.f, 0.f, 0.f};

  int arow = rt * 16 + (lane & 15);
  int kc = (lane >> 4) * 16;
#pragma unroll
  for (int ks = 0; ks < 4; ++ks) {
    int kb = ks * 64;
    f16x8 a = *(f16x8*)(Ap + ((arow * 256 + kb + kc) ^ ((arow & 7) << 4)));
#pragma unroll
    for (int ct = 0; ct < 8; ++ct) {
      int bcol = ct * 16 + (lane & 15);
      f16x8 b = *(f16x8*)(Bp + ((bcol * 256 + kb + kc) ^ ((bcol & 7) << 4)));
      acc[ct] = __builtin_amdgcn_mfma_f32_16x16x32_f16(a, b, acc[ct], 0, 0, 0);
    }
  }

  int orow0 = row0 + rt * 16 + (lane >> 4) * 4;
#pragma unroll
  for (int ct = 0; ct < 8; ++ct) {
    int col = ct * 16 + (lane & 15);
#pragma unroll
    for (int r = 0; r < 4; ++r) {
      int row = orow0 + r;
      if (row < n) outh[(size_t)row * 128 + col] = (_Float16)acc[ct][r];
    }
  }
}

// ---------- edge aggregation: wave-per-node, 16-edge windows (6 loads in flight) ----------
// 4 groups of 16 lanes; per 16-edge window group g reads csr int4s at e+2g and e+8+2g,
// gathers 4 rows (f16x8/lane) into 4 packed-f16 accumulators.
__global__ __launch_bounds__(256) void k_agg(const _Float16* __restrict__ hw,
                                             const int* __restrict__ prow,
                                             const int2* __restrict__ csr2,
                                             const float* __restrict__ dinv,
                                             const float* __restrict__ bias,
                                             _Float16* __restrict__ out,
                                             float* __restrict__ psumL, int n) {
  int wave = threadIdx.x >> 6;
  int lane = threadIdx.x & 63;
  int grp = lane >> 4;   // 0..3
  int l16 = lane & 15;   // 0..15
  int node = blockIdx.x * 4 + wave;
  float a[8];
#pragma unroll
  for (int j = 0; j < 8; ++j) a[j] = 0.f;

  if (node < n) {
    f16x8 aa = {0, 0, 0, 0, 0, 0, 0, 0};
    f16x8 ab = {0, 0, 0, 0, 0, 0, 0, 0};
    f16x8 ac = {0, 0, 0, 0, 0, 0, 0, 0};
    f16x8 ad = {0, 0, 0, 0, 0, 0, 0, 0};
    int e0 = prow[node], e1 = prow[node + 1];
    int len = e1 - e0;
    int e = e0;
    int end16 = e0 + (len & ~15);
    const char* base = (const char*)hw + l16 * 16;
    for (; e < end16; e += 16) {
      int4 p0 = *(const int4*)(csr2 + e + 2 * grp);        // edges e+2g, e+2g+1
      int4 p1 = *(const int4*)(csr2 + e + 8 + 2 * grp);    // edges e+8+2g, e+8+2g+1
      f16x8 v0 = *(const f16x8*)(base + (unsigned)p0.x);
      f16x8 v1 = *(const f16x8*)(base + (unsigned)p0.z);
      f16x8 v2 = *(const f16x8*)(base + (unsigned)p1.x);
      f16x8 v3 = *(const f16x8*)(base + (unsigned)p1.z);
      aa += v0 * (_Float16)__int_as_float(p0.y);
      ab += v1 * (_Float16)__int_as_float(p0.w);
      ac += v2 * (_Float16)__int_as_float(p1.y);
      ad += v3 * (_Float16)__int_as_float(p1.w);
    }
    if (len & 8) {
      int4 p0 = *(const int4*)(csr2 + e + 2 * grp);
      f16x8 v0 = *(const f16x8*)(base + (unsigned)p0.x);
      f16x8 v1 = *(const f16x8*)(base + (unsigned)p0.z);
      aa += v0 * (_Float16)__int_as_float(p0.y);
      ab += v1 * (_Float16)__int_as_float(p0.w);
      e += 8;
    }
    if (len & 4) {  // wave-uniform tail window of 4 edges
      int2 p = csr2[e + grp];
      f16x8 v = *(const f16x8*)(base + (unsigned)p.x);
      aa += v * (_Float16)__int_as_float(p.y);
    }
    aa = (aa + ab) + (ac + ad);
#pragma unroll
    for (int j = 0; j < 8; ++j) a[j] = (float)aa[j];
    // reduce across the 4 groups (lanes differ in bits 4,5)
#pragma unroll
    for (int j = 0; j < 8; ++j) {
      a[j] += __shfl_xor(a[j], 16);
      a[j] += __shfl_xor(a[j], 32);
    }
    float dn = dinv[node];
    float sn = dn * dn;
    f16x8 v = *(const f16x8*)(hw + (size_t)node * 128 + l16 * 8);
    float4 bb0 = *(const float4*)(bias + l16 * 8);
    float4 bb1 = *(const float4*)(bias + l16 * 8 + 4);
    a[0] += sn * (float)v[0] + bb0.x;
    a[1] += sn * (float)v[1] + bb0.y;
    a[2] += sn * (float)v[2] + bb0.z;
    a[3] += sn * (float)v[3] + bb0.w;
    a[4] += sn * (float)v[4] + bb1.x;
    a[5] += sn * (float)v[5] + bb1.y;
    a[6] += sn * (float)v[6] + bb1.z;
    a[7] += sn * (float)v[7] + bb1.w;
    if (grp == 0) {
      f16x8 ov;
#pragma unroll
      for (int j = 0; j < 8; ++j) ov[j] = (_Float16)a[j];
      *(f16x8*)(out + (size_t)node * 128 + l16 * 8) = ov;
    }
  }
  // fused BN stats (fp32 pre-rounding): LDS reduce, replicated atomics
  __shared__ float ss[4][128];
  __shared__ float sq[4][128];
  if (grp == 0) {
    bool live = (node < n);
    float v0 = live ? a[0] : 0.f, v1 = live ? a[1] : 0.f;
    float v2 = live ? a[2] : 0.f, v3 = live ? a[3] : 0.f;
    float v4 = live ? a[4] : 0.f, v5 = live ? a[5] : 0.f;
    float v6 = live ? a[6] : 0.f, v7 = live ? a[7] : 0.f;
    *(float4*)&ss[wave][l16 * 8] = make_float4(v0, v1, v2, v3);
    *(float4*)&ss[wave][l16 * 8 + 4] = make_float4(v4, v5, v6, v7);
    *(float4*)&sq[wave][l16 * 8] = make_float4(v0 * v0, v1 * v1, v2 * v2, v3 * v3);
    *(float4*)&sq[wave][l16 * 8 + 4] = make_float4(v4 * v4, v5 * v5, v6 * v6, v7 * v7);
  }
  __syncthreads();
  int t = threadIdx.x;
  if (t < 128) {
    float s = (ss[0][t] + ss[1][t]) + (ss[2][t] + ss[3][t]);
    float q = (sq[0][t] + sq[1][t]) + (sq[2][t] + sq[3][t]);
    int rep = blockIdx.x & (PS_REP - 1);
    atomicAdd(&psumL[rep * 128 + t], s);
    atomicAdd(&psumL[PS_REP * 128 + rep * 128 + t], q);
  }
}

// ---------- pooling (absorbs final BN2+residual): batch sorted -> segment reduction ----------
#define PCHUNK 128
__global__ __launch_bounds__(128) void k_pool(const float* __restrict__ h,
                                              const _Float16* __restrict__ t2h,
                                              const float* __restrict__ psumL,
                                              const float* __restrict__ gg,
                                              const float* __restrict__ be,
                                              const int* __restrict__ batch,
                                              float* __restrict__ sums,
                                              unsigned* __restrict__ maxenc,
                                              int* __restrict__ cnt, int n) {
  int c = threadIdx.x;
  __shared__ float sc_s[128], sh_s[128];
  {
    const float* psqL = psumL + PS_REP * 128;
    float s = 0.f, q = 0.f;
#pragma unroll 8
    for (int r = 0; r < PS_REP; ++r) {
      s += psumL[r * 128 + c];
      q += psqL[r * 128 + c];
    }
    float mu = s / (float)n;
    float var = q / (float)n - mu * mu;
    float rs = rsqrtf(var + EPSBN);
    float sc = gg[c] * rs;
    sc_s[c] = sc;
    sh_s[c] = be[c] - mu * sc;
  }
  __syncthreads();
  float scc = sc_s[c], shc = sh_s[c];

  int start = blockIdx.x * PCHUNK;
  if (start >= n) return;
  int end = start + PCHUNK;
  if (end > n) end = n;
  int cur = batch[start];
  float s = 0.f, mx = -FLT_MAX;
  int runlen = 0;
  for (int i = start; i < end; ++i) {
    int b = batch[i];
    if (b != cur) {
      atomicAdd(&sums[cur * 128 + c], s);
      atomicMax(&maxenc[cur * 128 + c], enc_f(mx));
      if (c == 0) atomicAdd(&cnt[cur], runlen);
      s = 0.f; mx = -FLT_MAX; runlen = 0; cur = b;
    }
    float v = h[(size_t)i * 128 + c] + scc * (float)t2h[(size_t)i * 128 + c] + shc;
    s += v;
    mx = fmaxf(mx, v);
    runlen++;
  }
  atomicAdd(&sums[cur * 128 + c], s);
  atomicMax(&maxenc[cur * 128 + c], enc_f(mx));
  if (c == 0) atomicAdd(&cnt[cur], runlen);
}

// ---------- readout MLP ----------
__global__ __launch_bounds__(256) void k_readout(const float* __restrict__ sums,
                                                 const unsigned* __restrict__ maxenc,
                                                 const int* __restrict__ cnt,
                                                 const float* __restrict__ Wa,
                                                 const float* __restrict__ ba,
                                                 const float* __restrict__ Wb,
                                                 const float* __restrict__ bb,
                                                 const float* __restrict__ Wc,
                                                 const float* __restrict__ bc,
                                                 float* __restrict__ out) {
  int g = blockIdx.x;
  int t = threadIdx.x;
  __shared__ float z[384];
  __shared__ float za[256];
  __shared__ float zb[128];
  float c = (float)(cnt[g] > 1 ? cnt[g] : 1);
  if (t < 128) {
    float s = sums[g * 128 + t];
    z[t] = s / c;
    z[128 + t] = dec_f(maxenc[g * 128 + t]);
    z[256 + t] = s;
  }
  __syncthreads();
  float accA = ba[t];
  for (int k = 0; k < 384; k++) accA += z[k] * Wa[k * 256 + t];
  za[t] = fmaxf(accA, 0.f);
  __syncthreads();
  if (t < 128) {
    float accB = bb[t];
    for (int k = 0; k < 256; k++) accB += za[k] * Wb[k * 128 + t];
    zb[t] = fmaxf(accB, 0.f);
  }
  __syncthreads();
  if (t < 64) {
    float p = zb[t] * Wc[t] + zb[t + 64] * Wc[t + 64];
    for (int off = 32; off > 0; off >>= 1) p += __shfl_down(p, off);
    if (t == 0) out[g] = p + bc[0];
  }
}

extern "C" void kernel_launch(void* const* d_in, const int* in_sizes, int n_in,
                              void* d_out, int out_size, void* d_ws, size_t ws_size,
                              hipStream_t stream) {
  const float* x   = (const float*)d_in[0];
  const int* edge  = (const int*)d_in[1];
  const int* batch = (const int*)d_in[2];
  const float* Wp  = (const float*)d_in[3];
  const float* bp  = (const float*)d_in[4];
  const float* W1  = (const float*)d_in[5];
  const float* b1  = (const float*)d_in[6];
  const float* g1  = (const float*)d_in[7];
  const float* be1 = (const float*)d_in[8];
  const float* W2  = (const float*)d_in[9];
  const float* b2  = (const float*)d_in[10];
  const float* g2  = (const float*)d_in[11];
  const float* be2 = (const float*)d_in[12];
  const float* Wa  = (const float*)d_in[13];
  const float* ba  = (const float*)d_in[14];
  const float* Wb  = (const float*)d_in[15];
  const float* bbp = (const float*)d_in[16];
  const float* Wc  = (const float*)d_in[17];
  const float* bc  = (const float*)d_in[18];
  float* out = (float*)d_out;

  const int N = in_sizes[0] / 128;
  const int E = in_sizes[1] / 2;
  const int* esrc = edge;
  const int* edst = edge + E;

  char* p = (char*)d_ws;
  auto carve = [&](size_t bytes) {
    char* r = p;
    p += (bytes + 255) & ~(size_t)255;
    return (void*)r;
  };
  float* h    = (float*)carve((size_t)N * 128 * 4);
  _Float16* t1h = (_Float16*)carve((size_t)N * 128 * 2);
  _Float16* t2h = (_Float16*)carve((size_t)N * 128 * 2);
  int2* csr2  = (int2*)carve(((size_t)E + 4 * (size_t)N) * 8);  // padded CSR
  int* deg     = (int*)carve((size_t)N * 4);
  float* dinv  = (float*)carve((size_t)N * 4);
  int* prow    = (int*)carve((size_t)(N + 1) * 4);
  int* cursor  = (int*)carve((size_t)N * 4);
  int* bsum    = (int*)carve(512 * 4);
  float* slab  = (float*)carve((size_t)16 * SLABF * 4);  // 16 BN slabs
  float* pools = (float*)carve((size_t)NGRAPH * 128 * 4);
  unsigned* poolm = (unsigned*)carve((size_t)NGRAPH * 128 * 4);
  int* poolc      = (int*)carve(NGRAPH * 4);
  _Float16* wt16  = (_Float16*)carve((size_t)17 * 128 * 128 * 2);

  const int NB = (N + 255) / 256;

  hipMemsetAsync(deg, 0, (size_t)N * 4, stream);
  hipMemsetAsync(cursor, 0, (size_t)N * 4, stream);
  hipMemsetAsync(slab, 0, (size_t)16 * SLABF * 4, stream);
  hipMemsetAsync(pools, 0, (size_t)NGRAPH * 128 * 4, stream);
  hipMemsetAsync(poolm, 0, (size_t)NGRAPH * 128 * 4, stream);
  hipMemsetAsync(poolc, 0, (size_t)NGRAPH * 4, stream);

  k_deg<<<(E + 255) / 256, 256, 0, stream>>>(edst, deg, E);
  k_dinv<<<NB, 256, 0, stream>>>(deg, dinv, N);
  k_scanA<<<NB, 256, 0, stream>>>(deg, prow, bsum, N);
  k_scanB<<<1, 512, 0, stream>>>(bsum, NB);
  k_scanC<<<NB, 256, 0, stream>>>(prow, bsum, deg, N);
  k_fill<<<(E + 255) / 256, 256, 0, stream>>>(esrc, edst, dinv, prow, cursor, csr2, E);
  k_pad<<<NB, 256, 0, stream>>>(deg, prow, csr2, N);
  k_wprep<<<17, 256, 0, stream>>>(W1, W2, Wp, wt16);

  const int GB = (N + 63) / 64;
  const int AB = (N + 3) / 4;
  const int PB = (N + PCHUNK - 1) / PCHUNK;

  k_gemmp<<<GB, 256, 0, stream>>>(x, wt16 + (size_t)16 * 16384, bp, h, N);
  k_gemmh<0><<<GB, 256, 0, stream>>>(h, wt16, nullptr, nullptr, nullptr, nullptr, t1h, N);

  for (int l = 0; l < 8; l++) {
    const _Float16* w2t = wt16 + (size_t)(l * 2 + 1) * 16384;
    float* slab1 = slab + (size_t)(2 * l) * SLABF;
    float* slab2 = slab + (size_t)(2 * l + 1) * SLABF;
    k_agg<<<AB, 256, 0, stream>>>(t1h, prow, csr2, dinv, b1 + l * 128, t2h, slab1, N);
    k_gemmh<1><<<GB, 256, 0, stream>>>(t2h, w2t, slab1, g1 + l * 128, be1 + l * 128, nullptr, t1h, N);
    k_agg<<<AB, 256, 0, stream>>>(t1h, prow, csr2, dinv, b2 + l * 128, t2h, slab2, N);
    if (l < 7) {
      const _Float16* w1n = wt16 + (size_t)((l + 1) * 2) * 16384;
      k_gemmh<2><<<GB, 256, 0, stream>>>(t2h, w1n, slab2, g2 + l * 128, be2 + l * 128, h, t1h, N);
    }
  }

  k_pool<<<PB, 128, 0, stream>>>(h, t2h, slab + (size_t)15 * SLABF, g2 + 7 * 128, be2 + 7 * 128,
                                 batch, pools, poolm, poolc, N);
  k_readout<<<NGRAPH, 256, 0, stream>>>(pools, poolm, poolc, Wa, ba, Wb, bbp, Wc, bc, out);
}

// Round 12
// 1691.644 us; speedup vs baseline: 1.0501x; 1.0153x over previous
//
#include <hip/hip_runtime.h>
#include <hip/hip_fp16.h>
#include <math.h>
#include <float.h>

#define HDIM 128
#define NGRAPH 256
#define EPSBN 1e-5f
#define PS_REP 32
#define SLABF (2 * PS_REP * 128)   // floats per BN slab (psum+psq)

typedef _Float16 f16x8 __attribute__((ext_vector_type(8)));
typedef _Float16 f16x4 __attribute__((ext_vector_type(4)));
typedef float f32x4 __attribute__((ext_vector_type(4)));

__device__ inline unsigned enc_f(float v) {
  unsigned u = __float_as_uint(v);
  return (u & 0x80000000u) ? ~u : (u | 0x80000000u);
}
__device__ inline float dec_f(unsigned e) {
  return __uint_as_float((e & 0x80000000u) ? (e ^ 0x80000000u) : ~e);
}

// ---------- degree / dinv ----------
__global__ void k_deg(const int* __restrict__ dst, int* __restrict__ deg, int E) {
  int i = blockIdx.x * blockDim.x + threadIdx.x;
  if (i < E) atomicAdd(&deg[dst[i]], 1);
}

__global__ void k_dinv(const int* __restrict__ deg, float* __restrict__ dinv, int n) {
  int i = blockIdx.x * blockDim.x + threadIdx.x;
  if (i < n) dinv[i] = rsqrtf((float)deg[i] + 1.0f);
}

// ---------- 2-level exclusive scan of PADDED deg (multiple of 4) -> prow ----------
__global__ void k_scanA(const int* __restrict__ deg, int* __restrict__ rowstart,
                        int* __restrict__ bsum, int n) {
  __shared__ int s[256];
  int t = threadIdx.x, i = blockIdx.x * 256 + t;
  int v = (i < n) ? ((deg[i] + 3) & ~3) : 0;
  s[t] = v;
  __syncthreads();
  for (int off = 1; off < 256; off <<= 1) {
    int x = (t >= off) ? s[t - off] : 0;
    __syncthreads();
    s[t] += x;
    __syncthreads();
  }
  if (i < n) rowstart[i] = s[t] - v;  // exclusive
  if (t == 255) bsum[blockIdx.x] = s[255];
}

__global__ void k_scanB(int* __restrict__ bsum, int nb) {
  __shared__ int s[512];
  int t = threadIdx.x;
  int v = (t < nb) ? bsum[t] : 0;
  s[t] = v;
  __syncthreads();
  for (int off = 1; off < 512; off <<= 1) {
    int x = (t >= off) ? s[t - off] : 0;
    __syncthreads();
    s[t] += x;
    __syncthreads();
  }
  if (t < nb) bsum[t] = s[t] - v;  // exclusive
}

__global__ void k_scanC(int* __restrict__ rowstart, const int* __restrict__ bsum,
                        const int* __restrict__ deg, int n) {
  int i = blockIdx.x * 256 + threadIdx.x;
  if (i < n) {
    int v = rowstart[i] + bsum[blockIdx.x];
    rowstart[i] = v;
    if (i == n - 1) rowstart[n] = v + ((deg[i] + 3) & ~3);
  }
}

// real edges -> padded CSR slots {src_byteoff, w} (single pass)
__global__ void k_fill(const int* __restrict__ src, const int* __restrict__ dst,
                       const float* __restrict__ dinv, const int* __restrict__ prow,
                       int* __restrict__ cursor, int2* __restrict__ csr2, int E) {
  int e = blockIdx.x * blockDim.x + threadIdx.x;
  if (e < E) {
    int d = dst[e], s = src[e];
    int pos = prow[d] + atomicAdd(&cursor[d], 1);
    csr2[pos] = make_int2(s << 8, __float_as_int(dinv[s] * dinv[d]));
  }
}

// pad slots deg[i]..degpad-1 with {self, 0}
__global__ void k_pad(const int* __restrict__ deg, const int* __restrict__ prow,
                      int2* __restrict__ csr2, int n) {
  int i = blockIdx.x * blockDim.x + threadIdx.x;
  if (i < n) {
    int d = deg[i], dp = (d + 3) & ~3;
    int base = prow[i];
    for (int j = d; j < dp; ++j) csr2[base + j] = make_int2(i << 8, 0);
  }
}

// ---------- weight prep: fp32 [k][col] -> fp16 [col][k], 17 matrices (16 layers + Wp) ----------
__global__ __launch_bounds__(256) void k_wprep(const float* __restrict__ W1,
                                               const float* __restrict__ W2,
                                               const float* __restrict__ Wp,
                                               _Float16* __restrict__ wt) {
  int m = blockIdx.x;
  const float* Wsrc = (m == 16) ? Wp : (((m & 1) ? W2 : W1) + (size_t)(m >> 1) * 16384);
  _Float16* Wdst = wt + (size_t)m * 16384;
  __shared__ _Float16 lds[128 * 132];
  int t = threadIdx.x;
  const float4* W4 = (const float4*)Wsrc;
  for (int it = 0; it < 16; ++it) {
    int idx = t + it * 256;
    int k = idx >> 5, c4 = idx & 31;
    float4 v = W4[idx];
    lds[(c4 * 4 + 0) * 132 + k] = (_Float16)v.x;
    lds[(c4 * 4 + 1) * 132 + k] = (_Float16)v.y;
    lds[(c4 * 4 + 2) * 132 + k] = (_Float16)v.z;
    lds[(c4 * 4 + 3) * 132 + k] = (_Float16)v.w;
  }
  __syncthreads();
  for (int it = 0; it < 16; ++it) {
    int idx = t + it * 256;
    int col = idx >> 5, k4 = idx & 31;
    f16x4 o;
    o[0] = lds[col * 132 + k4 * 4 + 0];
    o[1] = lds[col * 132 + k4 * 4 + 1];
    o[2] = lds[col * 132 + k4 * 4 + 2];
    o[3] = lds[col * 132 + k4 * 4 + 3];
    *(f16x4*)(Wdst + col * 128 + k4 * 4) = o;
  }
}

// ---------- MFMA projection: h16[N,128] = f16(x) @ Wp + bias (f16 out) ----------
__global__ __launch_bounds__(256) void k_gemmp(const float* __restrict__ in,
                                               const _Float16* __restrict__ wt,
                                               const float* __restrict__ bias,
                                               _Float16* __restrict__ outh, int n) {
  __shared__ _Float16 As[64 * 128];
  __shared__ _Float16 Bs[128 * 128];
  char* Ap = (char*)As;
  char* Bp = (char*)Bs;
  int tid = threadIdx.x;
  int lane = tid & 63;
  int rt = tid >> 6;
  int row0 = blockIdx.x * 64;

  for (int it = 0; it < 8; ++it) {
    int idx = tid + it * 256;
    int r = idx >> 5, c4 = idx & 31;
    int row = row0 + r;
    if (row >= n) row = n - 1;
    float4 v = *(const float4*)(in + (size_t)row * 128 + c4 * 4);
    f16x4 hv;
    hv[0] = (_Float16)v.x; hv[1] = (_Float16)v.y;
    hv[2] = (_Float16)v.z; hv[3] = (_Float16)v.w;
    *(f16x4*)(Ap + ((r * 256 + c4 * 8) ^ ((r & 7) << 4))) = hv;
  }
  for (int it = 0; it < 8; ++it) {
    int idx = tid + it * 256;
    int col = idx >> 4, k8 = idx & 15;
    f16x8 v = *(const f16x8*)(wt + col * 128 + k8 * 8);
    *(f16x8*)(Bp + ((col * 256 + k8 * 16) ^ ((col & 7) << 4))) = v;
  }
  __syncthreads();

  f32x4 acc[8];
#pragma unroll
  for (int ct = 0; ct < 8; ++ct) acc[ct] = (f32x4){0.f, 0.f, 0.f, 0.f};
  int arow = rt * 16 + (lane & 15);
  int kc = (lane >> 4) * 16;
#pragma unroll
  for (int ks = 0; ks < 4; ++ks) {
    int kb = ks * 64;
    f16x8 a = *(f16x8*)(Ap + ((arow * 256 + kb + kc) ^ ((arow & 7) << 4)));
#pragma unroll
    for (int ct = 0; ct < 8; ++ct) {
      int bcol = ct * 16 + (lane & 15);
      f16x8 b = *(f16x8*)(Bp + ((bcol * 256 + kb + kc) ^ ((bcol & 7) << 4)));
      acc[ct] = __builtin_amdgcn_mfma_f32_16x16x32_f16(a, b, acc[ct], 0, 0, 0);
    }
  }

  int orow0 = row0 + rt * 16 + (lane >> 4) * 4;
#pragma unroll
  for (int ct = 0; ct < 8; ++ct) {
    int col = ct * 16 + (lane & 15);
    float bb = bias[col];
#pragma unroll
    for (int r = 0; r < 4; ++r) {
      int row = orow0 + r;
      if (row < n) outh[(size_t)row * 128 + col] = (_Float16)(acc[ct][r] + bb);
    }
  }
}

// ---------- MFMA f16 GEMM with BN prologue (all inputs f16) ----------
// XFORM=0: in = h16, plain copy stage.
// XFORM=1: in = t2h; stage relu(in*sc+sh).
// XFORM=2: in = t2h; stage hres16 + in*sc+sh (BN2+residual); writes new hres16.
template <int XFORM>
__global__ __launch_bounds__(256) void k_gemmh(const _Float16* __restrict__ in,
                                               const _Float16* __restrict__ wt,
                                               const float* __restrict__ psumL,
                                               const float* __restrict__ gg,
                                               const float* __restrict__ be,
                                               _Float16* __restrict__ hres,
                                               _Float16* __restrict__ outh, int n) {
  __shared__ _Float16 As[64 * 128];
  __shared__ _Float16 Bs[128 * 128];
  __shared__ float sc_s[128], sh_s[128];
  char* Ap = (char*)As;
  char* Bp = (char*)Bs;
  int tid = threadIdx.x;
  int lane = tid & 63;
  int rt = tid >> 6;
  int row0 = blockIdx.x * 64;

  if (XFORM) {
    if (tid < 128) {
      const float* psqL = psumL + PS_REP * 128;
      float s = 0.f, q = 0.f;
#pragma unroll 8
      for (int r = 0; r < PS_REP; ++r) {
        s += psumL[r * 128 + tid];
        q += psqL[r * 128 + tid];
      }
      float mu = s / (float)n;
      float var = q / (float)n - mu * mu;
      float rs = rsqrtf(var + EPSBN);
      float sc = gg[tid] * rs;
      sc_s[tid] = sc;
      sh_s[tid] = be[tid] - mu * sc;
    }
    __syncthreads();
  }

  for (int it = 0; it < 4; ++it) {
    int idx = tid + it * 256;          // 1024 chunks of 8 cols
    int r = idx >> 4, c8 = idx & 15;
    int rrow = row0 + r;
    int row = (rrow >= n) ? (n - 1) : rrow;
    f16x8 tv = *(const f16x8*)(in + (size_t)row * 128 + c8 * 8);
    f16x8 o;
    if (XFORM == 0) {
      o = tv;
    } else {
      float4 s0 = *(const float4*)(sc_s + c8 * 8);
      float4 s1 = *(const float4*)(sc_s + c8 * 8 + 4);
      float4 h0 = *(const float4*)(sh_s + c8 * 8);
      float4 h1 = *(const float4*)(sh_s + c8 * 8 + 4);
      float v[8];
#pragma unroll
      for (int j = 0; j < 8; ++j) v[j] = (float)tv[j];
      v[0] = v[0] * s0.x + h0.x; v[1] = v[1] * s0.y + h0.y;
      v[2] = v[2] * s0.z + h0.z; v[3] = v[3] * s0.w + h0.w;
      v[4] = v[4] * s1.x + h1.x; v[5] = v[5] * s1.y + h1.y;
      v[6] = v[6] * s1.z + h1.z; v[7] = v[7] * s1.w + h1.w;
      if (XFORM == 1) {
#pragma unroll
        for (int j = 0; j < 8; ++j) v[j] = fmaxf(v[j], 0.f);
      }
      if (XFORM == 2) {
        f16x8 hv = *(const f16x8*)(hres + (size_t)row * 128 + c8 * 8);
#pragma unroll
        for (int j = 0; j < 8; ++j) v[j] += (float)hv[j];
      }
#pragma unroll
      for (int j = 0; j < 8; ++j) o[j] = (_Float16)v[j];
      if (XFORM == 2 && rrow < n)
        *(f16x8*)(hres + (size_t)row * 128 + c8 * 8) = o;
    }
    *(f16x8*)(Ap + ((r * 256 + c8 * 16) ^ ((r & 7) << 4))) = o;
  }
  for (int it = 0; it < 8; ++it) {
    int idx = tid + it * 256;
    int col = idx >> 4, k8 = idx & 15;
    f16x8 v = *(const f16x8*)(wt + col * 128 + k8 * 8);
    *(f16x8*)(Bp + ((col * 256 + k8 * 16) ^ ((col & 7) << 4))) = v;
  }
  __syncthreads();

  f32x4 acc[8];
#pragma unroll
  for (int ct = 0; ct < 8; ++ct) acc[ct] = (f32x4){0.f, 0.f, 0.f, 0.f};

  int arow = rt * 16 + (lane & 15);
  int kc = (lane >> 4) * 16;
#pragma unroll
  for (int ks = 0; ks < 4; ++ks) {
    int kb = ks * 64;
    f16x8 a = *(f16x8*)(Ap + ((arow * 256 + kb + kc) ^ ((arow & 7) << 4)));
#pragma unroll
    for (int ct = 0; ct < 8; ++ct) {
      int bcol = ct * 16 + (lane & 15);
      f16x8 b = *(f16x8*)(Bp + ((bcol * 256 + kb + kc) ^ ((bcol & 7) << 4)));
      acc[ct] = __builtin_amdgcn_mfma_f32_16x16x32_f16(a, b, acc[ct], 0, 0, 0);
    }
  }

  int orow0 = row0 + rt * 16 + (lane >> 4) * 4;
#pragma unroll
  for (int ct = 0; ct < 8; ++ct) {
    int col = ct * 16 + (lane & 15);
#pragma unroll
    for (int r = 0; r < 4; ++r) {
      int row = orow0 + r;
      if (row < n) outh[(size_t)row * 128 + col] = (_Float16)acc[ct][r];
    }
  }
}

// ---------- edge aggregation: wave-per-node, 32-edge windows (12 loads in flight) ----------
__global__ __launch_bounds__(256) void k_agg(const _Float16* __restrict__ hw,
                                             const int* __restrict__ prow,
                                             const int2* __restrict__ csr2,
                                             const float* __restrict__ dinv,
                                             const float* __restrict__ bias,
                                             _Float16* __restrict__ out,
                                             float* __restrict__ psumL, int n) {
  int wave = threadIdx.x >> 6;
  int lane = threadIdx.x & 63;
  int grp = lane >> 4;   // 0..3
  int l16 = lane & 15;   // 0..15
  int node = blockIdx.x * 4 + wave;
  float a[8];
#pragma unroll
  for (int j = 0; j < 8; ++j) a[j] = 0.f;

  if (node < n) {
    f16x8 aa = {0, 0, 0, 0, 0, 0, 0, 0};
    f16x8 ab = {0, 0, 0, 0, 0, 0, 0, 0};
    f16x8 ac = {0, 0, 0, 0, 0, 0, 0, 0};
    f16x8 ad = {0, 0, 0, 0, 0, 0, 0, 0};
    int e0 = prow[node], e1 = prow[node + 1];
    int len = e1 - e0;
    int e = e0;
    int end32 = e0 + (len & ~31);
    const char* base = (const char*)hw + l16 * 16;
    for (; e < end32; e += 32) {
      int4 p0 = *(const int4*)(csr2 + e + 2 * grp);
      int4 p1 = *(const int4*)(csr2 + e + 8 + 2 * grp);
      int4 p2 = *(const int4*)(csr2 + e + 16 + 2 * grp);
      int4 p3 = *(const int4*)(csr2 + e + 24 + 2 * grp);
      f16x8 v0 = *(const f16x8*)(base + (unsigned)p0.x);
      f16x8 v1 = *(const f16x8*)(base + (unsigned)p0.z);
      f16x8 v2 = *(const f16x8*)(base + (unsigned)p1.x);
      f16x8 v3 = *(const f16x8*)(base + (unsigned)p1.z);
      f16x8 v4 = *(const f16x8*)(base + (unsigned)p2.x);
      f16x8 v5 = *(const f16x8*)(base + (unsigned)p2.z);
      f16x8 v6 = *(const f16x8*)(base + (unsigned)p3.x);
      f16x8 v7 = *(const f16x8*)(base + (unsigned)p3.z);
      aa += v0 * (_Float16)__int_as_float(p0.y);
      ab += v1 * (_Float16)__int_as_float(p0.w);
      ac += v2 * (_Float16)__int_as_float(p1.y);
      ad += v3 * (_Float16)__int_as_float(p1.w);
      aa += v4 * (_Float16)__int_as_float(p2.y);
      ab += v5 * (_Float16)__int_as_float(p2.w);
      ac += v6 * (_Float16)__int_as_float(p3.y);
      ad += v7 * (_Float16)__int_as_float(p3.w);
    }
    if (len & 16) {
      int4 p0 = *(const int4*)(csr2 + e + 2 * grp);
      int4 p1 = *(const int4*)(csr2 + e + 8 + 2 * grp);
      f16x8 v0 = *(const f16x8*)(base + (unsigned)p0.x);
      f16x8 v1 = *(const f16x8*)(base + (unsigned)p0.z);
      f16x8 v2 = *(const f16x8*)(base + (unsigned)p1.x);
      f16x8 v3 = *(const f16x8*)(base + (unsigned)p1.z);
      aa += v0 * (_Float16)__int_as_float(p0.y);
      ab += v1 * (_Float16)__int_as_float(p0.w);
      ac += v2 * (_Float16)__int_as_float(p1.y);
      ad += v3 * (_Float16)__int_as_float(p1.w);
      e += 16;
    }
    if (len & 8) {
      int4 p0 = *(const int4*)(csr2 + e + 2 * grp);
      f16x8 v0 = *(const f16x8*)(base + (unsigned)p0.x);
      f16x8 v1 = *(const f16x8*)(base + (unsigned)p0.z);
      aa += v0 * (_Float16)__int_as_float(p0.y);
      ab += v1 * (_Float16)__int_as_float(p0.w);
      e += 8;
    }
    if (len & 4) {  // wave-uniform tail window of 4 edges
      int2 p = csr2[e + grp];
      f16x8 v = *(const f16x8*)(base + (unsigned)p.x);
      aa += v * (_Float16)__int_as_float(p.y);
    }
    aa = (aa + ab) + (ac + ad);
#pragma unroll
    for (int j = 0; j < 8; ++j) a[j] = (float)aa[j];
    // reduce across the 4 groups (lanes differ in bits 4,5)
#pragma unroll
    for (int j = 0; j < 8; ++j) {
      a[j] += __shfl_xor(a[j], 16);
      a[j] += __shfl_xor(a[j], 32);
    }
    float dn = dinv[node];
    float sn = dn * dn;
    f16x8 v = *(const f16x8*)(hw + (size_t)node * 128 + l16 * 8);
    float4 bb0 = *(const float4*)(bias + l16 * 8);
    float4 bb1 = *(const float4*)(bias + l16 * 8 + 4);
    a[0] += sn * (float)v[0] + bb0.x;
    a[1] += sn * (float)v[1] + bb0.y;
    a[2] += sn * (float)v[2] + bb0.z;
    a[3] += sn * (float)v[3] + bb0.w;
    a[4] += sn * (float)v[4] + bb1.x;
    a[5] += sn * (float)v[5] + bb1.y;
    a[6] += sn * (float)v[6] + bb1.z;
    a[7] += sn * (float)v[7] + bb1.w;
    if (grp == 0) {
      f16x8 ov;
#pragma unroll
      for (int j = 0; j < 8; ++j) ov[j] = (_Float16)a[j];
      *(f16x8*)(out + (size_t)node * 128 + l16 * 8) = ov;
    }
  }
  // fused BN stats (fp32 pre-rounding): LDS reduce, replicated atomics
  __shared__ float ss[4][128];
  __shared__ float sq[4][128];
  if (grp == 0) {
    bool live = (node < n);
    float v0 = live ? a[0] : 0.f, v1 = live ? a[1] : 0.f;
    float v2 = live ? a[2] : 0.f, v3 = live ? a[3] : 0.f;
    float v4 = live ? a[4] : 0.f, v5 = live ? a[5] : 0.f;
    float v6 = live ? a[6] : 0.f, v7 = live ? a[7] : 0.f;
    *(float4*)&ss[wave][l16 * 8] = make_float4(v0, v1, v2, v3);
    *(float4*)&ss[wave][l16 * 8 + 4] = make_float4(v4, v5, v6, v7);
    *(float4*)&sq[wave][l16 * 8] = make_float4(v0 * v0, v1 * v1, v2 * v2, v3 * v3);
    *(float4*)&sq[wave][l16 * 8 + 4] = make_float4(v4 * v4, v5 * v5, v6 * v6, v7 * v7);
  }
  __syncthreads();
  int t = threadIdx.x;
  if (t < 128) {
    float s = (ss[0][t] + ss[1][t]) + (ss[2][t] + ss[3][t]);
    float q = (sq[0][t] + sq[1][t]) + (sq[2][t] + sq[3][t]);
    int rep = blockIdx.x & (PS_REP - 1);
    atomicAdd(&psumL[rep * 128 + t], s);
    atomicAdd(&psumL[PS_REP * 128 + rep * 128 + t], q);
  }
}

// ---------- pooling (absorbs final BN2+residual): batch sorted -> segment reduction ----------
#define PCHUNK 128
__global__ __launch_bounds__(128) void k_pool(const _Float16* __restrict__ h16,
                                              const _Float16* __restrict__ t2h,
                                              const float* __restrict__ psumL,
                                              const float* __restrict__ gg,
                                              const float* __restrict__ be,
                                              const int* __restrict__ batch,
                                              float* __restrict__ sums,
                                              unsigned* __restrict__ maxenc,
                                              int* __restrict__ cnt, int n) {
  int c = threadIdx.x;
  __shared__ float sc_s[128], sh_s[128];
  {
    const float* psqL = psumL + PS_REP * 128;
    float s = 0.f, q = 0.f;
#pragma unroll 8
    for (int r = 0; r < PS_REP; ++r) {
      s += psumL[r * 128 + c];
      q += psqL[r * 128 + c];
    }
    float mu = s / (float)n;
    float var = q / (float)n - mu * mu;
    float rs = rsqrtf(var + EPSBN);
    float sc = gg[c] * rs;
    sc_s[c] = sc;
    sh_s[c] = be[c] - mu * sc;
  }
  __syncthreads();
  float scc = sc_s[c], shc = sh_s[c];

  int start = blockIdx.x * PCHUNK;
  if (start >= n) return;
  int end = start + PCHUNK;
  if (end > n) end = n;
  int cur = batch[start];
  float s = 0.f, mx = -FLT_MAX;
  int runlen = 0;
  for (int i = start; i < end; ++i) {
    int b = batch[i];
    if (b != cur) {
      atomicAdd(&sums[cur * 128 + c], s);
      atomicMax(&maxenc[cur * 128 + c], enc_f(mx));
      if (c == 0) atomicAdd(&cnt[cur], runlen);
      s = 0.f; mx = -FLT_MAX; runlen = 0; cur = b;
    }
    float v = (float)h16[(size_t)i * 128 + c] + scc * (float)t2h[(size_t)i * 128 + c] + shc;
    s += v;
    mx = fmaxf(mx, v);
    runlen++;
  }
  atomicAdd(&sums[cur * 128 + c], s);
  atomicMax(&maxenc[cur * 128 + c], enc_f(mx));
  if (c == 0) atomicAdd(&cnt[cur], runlen);
}

// ---------- readout MLP ----------
__global__ __launch_bounds__(256) void k_readout(const float* __restrict__ sums,
                                                 const unsigned* __restrict__ maxenc,
                                                 const int* __restrict__ cnt,
                                                 const float* __restrict__ Wa,
                                                 const float* __restrict__ ba,
                                                 const float* __restrict__ Wb,
                                                 const float* __restrict__ bb,
                                                 const float* __restrict__ Wc,
                                                 const float* __restrict__ bc,
                                                 float* __restrict__ out) {
  int g = blockIdx.x;
  int t = threadIdx.x;
  __shared__ float z[384];
  __shared__ float za[256];
  __shared__ float zb[128];
  float c = (float)(cnt[g] > 1 ? cnt[g] : 1);
  if (t < 128) {
    float s = sums[g * 128 + t];
    z[t] = s / c;
    z[128 + t] = dec_f(maxenc[g * 128 + t]);
    z[256 + t] = s;
  }
  __syncthreads();
  float accA = ba[t];
  for (int k = 0; k < 384; k++) accA += z[k] * Wa[k * 256 + t];
  za[t] = fmaxf(accA, 0.f);
  __syncthreads();
  if (t < 128) {
    float accB = bb[t];
    for (int k = 0; k < 256; k++) accB += za[k] * Wb[k * 128 + t];
    zb[t] = fmaxf(accB, 0.f);
  }
  __syncthreads();
  if (t < 64) {
    float p = zb[t] * Wc[t] + zb[t + 64] * Wc[t + 64];
    for (int off = 32; off > 0; off >>= 1) p += __shfl_down(p, off);
    if (t == 0) out[g] = p + bc[0];
  }
}

extern "C" void kernel_launch(void* const* d_in, const int* in_sizes, int n_in,
                              void* d_out, int out_size, void* d_ws, size_t ws_size,
                              hipStream_t stream) {
  const float* x   = (const float*)d_in[0];
  const int* edge  = (const int*)d_in[1];
  const int* batch = (const int*)d_in[2];
  const float* Wp  = (const float*)d_in[3];
  const float* bp  = (const float*)d_in[4];
  const float* W1  = (const float*)d_in[5];
  const float* b1  = (const float*)d_in[6];
  const float* g1  = (const float*)d_in[7];
  const float* be1 = (const float*)d_in[8];
  const float* W2  = (const float*)d_in[9];
  const float* b2  = (const float*)d_in[10];
  const float* g2  = (const float*)d_in[11];
  const float* be2 = (const float*)d_in[12];
  const float* Wa  = (const float*)d_in[13];
  const float* ba  = (const float*)d_in[14];
  const float* Wb  = (const float*)d_in[15];
  const float* bbp = (const float*)d_in[16];
  const float* Wc  = (const float*)d_in[17];
  const float* bc  = (const float*)d_in[18];
  float* out = (float*)d_out;

  const int N = in_sizes[0] / 128;
  const int E = in_sizes[1] / 2;
  const int* esrc = edge;
  const int* edst = edge + E;

  char* p = (char*)d_ws;
  auto carve = [&](size_t bytes) {
    char* r = p;
    p += (bytes + 255) & ~(size_t)255;
    return (void*)r;
  };
  _Float16* h16 = (_Float16*)carve((size_t)N * 128 * 2);
  _Float16* t1h = (_Float16*)carve((size_t)N * 128 * 2);
  _Float16* t2h = (_Float16*)carve((size_t)N * 128 * 2);
  int2* csr2  = (int2*)carve(((size_t)E + 4 * (size_t)N) * 8);  // padded CSR
  int* deg     = (int*)carve((size_t)N * 4);
  float* dinv  = (float*)carve((size_t)N * 4);
  int* prow    = (int*)carve((size_t)(N + 1) * 4);
  int* cursor  = (int*)carve((size_t)N * 4);
  int* bsum    = (int*)carve(512 * 4);
  float* slab  = (float*)carve((size_t)16 * SLABF * 4);  // 16 BN slabs
  float* pools = (float*)carve((size_t)NGRAPH * 128 * 4);
  unsigned* poolm = (unsigned*)carve((size_t)NGRAPH * 128 * 4);
  int* poolc      = (int*)carve(NGRAPH * 4);
  _Float16* wt16  = (_Float16*)carve((size_t)17 * 128 * 128 * 2);

  const int NB = (N + 255) / 256;

  hipMemsetAsync(deg, 0, (size_t)N * 4, stream);
  hipMemsetAsync(cursor, 0, (size_t)N * 4, stream);
  hipMemsetAsync(slab, 0, (size_t)16 * SLABF * 4, stream);
  hipMemsetAsync(pools, 0, (size_t)NGRAPH * 128 * 4, stream);
  hipMemsetAsync(poolm, 0, (size_t)NGRAPH * 128 * 4, stream);
  hipMemsetAsync(poolc, 0, (size_t)NGRAPH * 4, stream);

  k_deg<<<(E + 255) / 256, 256, 0, stream>>>(edst, deg, E);
  k_dinv<<<NB, 256, 0, stream>>>(deg, dinv, N);
  k_scanA<<<NB, 256, 0, stream>>>(deg, prow, bsum, N);
  k_scanB<<<1, 512, 0, stream>>>(bsum, NB);
  k_scanC<<<NB, 256, 0, stream>>>(prow, bsum, deg, N);
  k_fill<<<(E + 255) / 256, 256, 0, stream>>>(esrc, edst, dinv, prow, cursor, csr2, E);
  k_pad<<<NB, 256, 0, stream>>>(deg, prow, csr2, N);
  k_wprep<<<17, 256, 0, stream>>>(W1, W2, Wp, wt16);

  const int GB = (N + 63) / 64;
  const int AB = (N + 3) / 4;
  const int PB = (N + PCHUNK - 1) / PCHUNK;

  k_gemmp<<<GB, 256, 0, stream>>>(x, wt16 + (size_t)16 * 16384, bp, h16, N);
  k_gemmh<0><<<GB, 256, 0, stream>>>(h16, wt16, nullptr, nullptr, nullptr, nullptr, t1h, N);

  for (int l = 0; l < 8; l++) {
    const _Float16* w2t = wt16 + (size_t)(l * 2 + 1) * 16384;
    float* slab1 = slab + (size_t)(2 * l) * SLABF;
    float* slab2 = slab + (size_t)(2 * l + 1) * SLABF;
    k_agg<<<AB, 256, 0, stream>>>(t1h, prow, csr2, dinv, b1 + l * 128, t2h, slab1, N);
    k_gemmh<1><<<GB, 256, 0, stream>>>(t2h, w2t, slab1, g1 + l * 128, be1 + l * 128, nullptr, t1h, N);
    k_agg<<<AB, 256, 0, stream>>>(t1h, prow, csr2, dinv, b2 + l * 128, t2h, slab2, N);
    if (l < 7) {
      const _Float16* w1n = wt16 + (size_t)((l + 1) * 2) * 16384;
      k_gemmh<2><<<GB, 256, 0, stream>>>(t2h, w1n, slab2, g2 + l * 128, be2 + l * 128, h16, t1h, N);
    }
  }

  k_pool<<<PB, 128, 0, stream>>>(h16, t2h, slab + (size_t)15 * SLABF, g2 + 7 * 128, be2 + 7 * 128,
                                 batch, pools, poolm, poolc, N);
  k_readout<<<NGRAPH, 256, 0, stream>>>(pools, poolm, poolc, Wa, ba, Wb, bbp, Wc, bc, out);
}